// Round 8
// baseline (295.122 us; speedup 1.0000x reference)
//
#include <hip/hip_runtime.h>
#include <hip/hip_fp16.h>

// DepTreeLSTM on MI355X — R23: occupancy restructure. NP 16->8, grid tree
// 1024->2048 blocks, LDS 35840->~17.9KB, __launch_bounds__(256,5) forcing
// VGPR<=102 -> 5 waves/SIMD (was 4): the ~48% pipe-idle is barrier convoy
// at 4-way inter-block overlap/SIMD; 5 independent blocks/SIMD raises it.
// All level row-maps halve (one 16-row MFMA block: 8 pairs x 2 slots);
// single-position levels pad rows 8..15 (clamped reads, qd<2 write guard).
// Prefetch state shrinks: pxu ring-2 (1-ahead, R16-proven) + in-level pxd
// = 24 VGPR (was 72). rs/oc/parity schedule identical to R21. R22's
// setprio dropped (timed-neutral, node-confounded rocprof).
// prep: pack weights->fp16 (gate-interleaved, exp2-scaled), 768 blocks.
// xp_gemm: M=32 tiles / grid 1024, A staged from fp32 with cvt,
//   B via global_load_lds; XOR-8 granule swizzle.
// tree_kernel: 2048 blocks x 8 pairs, ping-pong LDS h state, creg c-state,
//   1 lgkm-only barrier/level, up 1-ahead prefetch, U frags hoisted.

typedef _Float16 f16x8 __attribute__((ext_vector_type(8)));
typedef _Float16 f16x4 __attribute__((ext_vector_type(4)));
typedef _Float16 f16x2 __attribute__((ext_vector_type(2)));
typedef float f32x4 __attribute__((ext_vector_type(4)));

#define NP 8    // pairs per tree block
#define N2K 2.8853900817779268f   // 2*log2(e); exp2(-N2K*x) = e^{-2x}

__device__ __forceinline__ void async16(const void* g, void* l) {
    __builtin_amdgcn_global_load_lds(
        (const __attribute__((address_space(1))) void*)g,
        (__attribute__((address_space(3))) void*)l, 16, 0, 0);
}
__device__ __forceinline__ void lgkm_barrier() {
    asm volatile("s_waitcnt lgkmcnt(0)\n\ts_barrier" ::: "memory");
}
__device__ __forceinline__ f32x4 exp2v(f32x4 x) {
    f32x4 y;
    y[0] = __builtin_amdgcn_exp2f(x[0]);
    y[1] = __builtin_amdgcn_exp2f(x[1]);
    y[2] = __builtin_amdgcn_exp2f(x[2]);
    y[3] = __builtin_amdgcn_exp2f(x[3]);
    return y;
}
__device__ __forceinline__ f32x4 rcpv(f32x4 x) {
    f32x4 y;
    y[0] = __builtin_amdgcn_rcpf(x[0]);
    y[1] = __builtin_amdgcn_rcpf(x[1]);
    y[2] = __builtin_amdgcn_rcpf(x[2]);
    y[3] = __builtin_amdgcn_rcpf(x[3]);
    return y;
}

// ---- prep: pack weights/bias to fp16, gate-interleaved cols, exp2-scaled ----
// Gate scale: I,O,F cols *= -log2e; U cols *= -2log2e. Applied identically to
// W (->Bx), U (->Upk) and b (->pb) so preacts land in exp2 domain:
//   sigm(x)  = 1/(1+exp2(x'))        x' = -log2e * x
//   tanh(u)  = (1-exp2(u'))/(1+exp2(u'))   u' = -2log2e * u
__global__ __launch_bounds__(256) void prep_kernel(
    const float* __restrict__ Wi_u, const float* __restrict__ Ui_u,
    const float* __restrict__ bi_u, const float* __restrict__ Wf_u,
    const float* __restrict__ Uf_u, const float* __restrict__ bf_u,
    const float* __restrict__ Wi_d, const float* __restrict__ Ui_d,
    const float* __restrict__ bi_d, const float* __restrict__ Wf_d,
    const float* __restrict__ Uf_d, const float* __restrict__ bf_d,
    _Float16* __restrict__ Bx, _Float16* __restrict__ Upk,
    float* __restrict__ pb)
{
    int idx = blockIdx.x * 256 + threadIdx.x;     // 196608 total
    if (idx < 512) {
        int d = idx >> 8, c = idx & 255, u = c >> 2, g = c & 3;
        const float* bio = d ? bi_d : bi_u;
        const float* bf  = d ? bf_d : bf_u;
        float s = (g == 2) ? -N2K : -0.5f * N2K;
        pb[idx] = s * ((g < 3) ? bio[g * 64 + u] : bf[u]);
    }
    if (idx < 163840) {                            // Bx: [dir][col256][k320]
        int d = idx / 81920, r1 = idx % 81920;
        int c = r1 / 320, k = r1 % 320, u = c >> 2, g = c & 3;
        const float* Wio = d ? Wi_d : Wi_u;
        const float* Wf  = d ? Wf_d : Wf_u;
        float s = (g == 2) ? -N2K : -0.5f * N2K;
        Bx[idx] = (_Float16)(s * ((g < 3) ? Wio[k * 192 + g * 64 + u]
                                          : Wf[k * 64 + u]));
    } else {                                       // Upk: 2*4*64*64
        int j = idx - 163840;
        int d = j >> 14, r2 = j & 16383;
        int g = r2 >> 12, u = (r2 >> 6) & 63, k = r2 & 63;
        const float* Uio = d ? Ui_d : Ui_u;
        const float* Uf  = d ? Uf_d : Uf_u;
        float s = (g == 2) ? -N2K : -0.5f * N2K;
        Upk[j] = (_Float16)(s * ((g < 3) ? Uio[k * 192 + g * 64 + u]
                                         : Uf[k * 64 + u]));
    }
}

// ---- XP = [tok|oh|dep] @ Bx + pb : M=32 tiles, K=320, N=256; grid 1024 ----
__global__ __launch_bounds__(256, 2) void xp_gemm(
    const float* __restrict__ tok, const float* __restrict__ oh,
    const float* __restrict__ dep,
    const _Float16* __restrict__ Bx, const float* __restrict__ pb,
    _Float16* __restrict__ XP)
{
    __shared__ _Float16 At[32 * 64];      // 4 KB
    __shared__ _Float16 Btl[256 * 64];    // 32 KB
    const int dir = blockIdx.x & 1, mt = blockIdx.x >> 1;
    const int tid = threadIdx.x, lane = tid & 63, w = tid >> 6;
    const int l15 = lane & 15, qd = lane >> 4;
    const int rsub = lane >> 3, pg = lane & 7;
    const int kg = (pg - rsub) & 7;                  // logical granule in tile
    const int koff = kg * 8;
    const int rowbase = mt * 32;
    const _Float16* Bb = Bx + (size_t)dir * 81920 + (w * 64 + rsub) * 320 + koff;

    f32x4 acc[2][4];
    #pragma unroll
    for (int i = 0; i < 2; ++i)
        #pragma unroll
        for (int j = 0; j < 4; ++j) acc[i][j] = (f32x4){0.f, 0.f, 0.f, 0.f};

    #pragma unroll
    for (int kt = 0; kt < 5; ++kt) {
        // ---- A stage: fp32 source -> cvt -> swizzled LDS (1 row/lane) ----
        {
            int row = rowbase + w * 8 + rsub;              // bt index
            int g = kt * 8 + kg;                           // granule 0..39
            const float* src = (g < 32) ? tok + (size_t)row * 256 + g * 8
                             : (g < 36) ? oh  + (size_t)row * 32 + (g - 32) * 8
                                        : dep + (size_t)row * 32 + (g - 36) * 8;
            float4 f0 = *(const float4*)src;
            float4 f1 = *(const float4*)(src + 4);
            f16x8 v;
            v[0] = (_Float16)f0.x; v[1] = (_Float16)f0.y;
            v[2] = (_Float16)f0.z; v[3] = (_Float16)f0.w;
            v[4] = (_Float16)f1.x; v[5] = (_Float16)f1.y;
            v[6] = (_Float16)f1.z; v[7] = (_Float16)f1.w;
            *(f16x8*)&At[(w * 8 + rsub) * 64 + pg * 8] = v;
        }
        // ---- B stage: async16 from packed Bx ----
        #pragma unroll
        for (int is = 0; is < 8; ++is)
            async16(Bb + (size_t)is * 8 * 320 + kt * 64,
                    &Btl[(w * 64 + is * 8) * 64]);
        __syncthreads();
        #pragma unroll
        for (int s = 0; s < 2; ++s) {
            const int g0 = s * 4 + qd;
            f16x8 af[2];
            #pragma unroll
            for (int i = 0; i < 2; ++i) {
                int R = i * 16 + l15;
                af[i] = *(const f16x8*)&At[R * 64 + ((g0 + R) & 7) * 8];
            }
            #pragma unroll
            for (int j = 0; j < 4; ++j) {
                int C = j * 64 + w * 16 + l15;
                f16x8 bf = *(const f16x8*)&Btl[C * 64 + ((g0 + C) & 7) * 8];
                #pragma unroll
                for (int i = 0; i < 2; ++i)
                    acc[i][j] = __builtin_amdgcn_mfma_f32_16x16x32_f16(
                        af[i], bf, acc[i][j], 0, 0, 0);
            }
        }
        __syncthreads();
    }
    #pragma unroll
    for (int i = 0; i < 2; ++i)
        #pragma unroll
        for (int j = 0; j < 4; ++j) {
            int colp = j * 64 + w * 16 + l15;
            float bias = pb[dir * 256 + colp];
            #pragma unroll
            for (int r = 0; r < 4; ++r) {
                int row = rowbase + i * 16 + qd * 4 + r;
                XP[(size_t)row * 512 + dir * 256 + colp] =
                    (_Float16)(acc[i][j][r] + bias);
            }
        }
}

// ---- gather XP preacts for one side of one level into registers ----
// TWO=1: two-position level (16 rows = 8 pl x 2 slots); TWO=0: single
// position (rows 8..15 duplicate 0..7, later discarded).
template<int TWO>
__device__ __forceinline__ void gather_xp(
    const char* __restrict__ XPd, const int (*btl)[NP],
    int p0, int p1, int unit, int qd, f16x4* px)
{
    #pragma unroll
    for (int r = 0; r < 4; ++r) {
        int row = qd * 4 + r;                        // 0..15
        int pl  = TWO ? (row >> 1) : (row & 7);
        int pos = TWO ? ((row & 1) ? p1 : p0) : p0;
        px[r] = *(const f16x4*)(XPd + btl[pos][pl] + unit * 8);
    }
}

// ---- compute one side of one level (state read parity -> write parity) ----
// Preacts arrive exp2-scaled (see prep_kernel). Cell update with shared rcp:
//   a=2^I', b=2^U', c=2^F';  cn = [(1-b)(1+c) + cin(1+a)(1+b)]
//                                 / [(1+a)(1+b)(1+c)]
//   e=2^{-N2K*cn}, o=2^O';   h  = (1-e) / [(1+e)(1+o)]
// No-carry level (rs0<0): CIN==0 -> EC cancels: CN=(1-EB)/PQ.
// TWO=0 (single position): MFMA rows 8..15 are clamped duplicates
// (rows independent in MFMA); threads qd>=2 skip all writes.
// c state: TWO=1 cells are thread-local across levels -> f16x2 regs
// (crR/crW idx r>>1, half=slot). cregr: read c from regs. cwEn: mirror c to
// LDS (next consumer is a TWO=0/root level, cross-mapped).
template<int TWO>
__device__ __forceinline__ void side_level(
    const f16x8 (*bfr)[4], const f16x4* px,
    const _Float16 (*hR)[68], const _Float16 (*cR)[68],
    _Float16 (*hW)[68], _Float16 (*cWl)[68],
    f16x2* crR, f16x2* crW, int cregr, int cwEn,
    float* __restrict__ out, int pair0,
    int rs0, int rs1, int oc0, int oc1,
    int unit, int l15, int qd)
{
    f32x4 acc[4];
    #pragma unroll
    for (int r = 0; r < 4; ++r) {
        f16x4 g4 = px[r];
        acc[0][r] = (float)g4[0];
        acc[1][r] = (float)g4[1];
        acc[2][r] = (float)g4[2];
        acc[3][r] = (float)g4[3];
    }

    if (rs0 >= 0) {
        #pragma unroll
        for (int s = 0; s < 2; ++s) {
            int R = l15;
            int arow = TWO ? ((R & ~1) | ((R & 1) ? rs1 : rs0))
                           : ((R & 7) * 2 + rs0);
            f16x8 af = *(const f16x8*)&hR[arow][s * 32 + qd * 8];
            #pragma unroll
            for (int g = 0; g < 4; ++g)
                acc[g] = __builtin_amdgcn_mfma_f32_16x16x32_f16(
                    af, bfr[s][g], acc[g], 0, 0, 0);
        }
    }

    f32x4 EA = exp2v(acc[0]);                   // e^{-I}
    f32x4 EO = exp2v(acc[1]);                   // e^{-O}
    f32x4 EB = exp2v(acc[2]);                   // e^{-2U}
    f32x4 PQ = (1.f + EA) * (1.f + EB);
    f32x4 CN;
    if (rs0 < 0) {
        CN = (1.f - EB) * rcpv(PQ);             // EC cancels when CIN==0
    } else {
        f32x4 CIN;
        #pragma unroll
        for (int r = 0; r < 4; ++r) {
            int row = qd * 4 + r;
            if (TWO) {
                int rs = (r & 1) ? rs1 : rs0;   // row&1 == r&1
                CIN[r] = cregr ? (float)crR[r >> 1][rs]
                               : (float)cR[(row >> 1) * 2 + rs][unit];
            } else {
                CIN[r] = (float)cR[(row & 7) * 2 + rs0][unit];
            }
        }
        f32x4 EC = exp2v(acc[3]);               // e^{-F}
        f32x4 PC = 1.f + EC;
        f32x4 NUM = CIN * PQ + (1.f - EB) * PC;
        CN = NUM * rcpv(PQ * PC);
    }
    f32x4 EE = exp2v(-N2K * CN);                // e^{-2cn}
    f32x4 H = (1.f - EE) * rcpv((1.f + EE) * (1.f + EO));

    if (TWO || qd < 2) {                        // TWO=0: rows>=8 invalid
        #pragma unroll
        for (int r = 0; r < 4; ++r) {
            int row = qd * 4 + r;
            int pl   = TWO ? (row >> 1) : row;
            int slot = TWO ? (row & 1) : 0;
            int oc = slot ? oc1 : oc0;
            if (oc >= 0) {
                out[(size_t)(pair0 + pl) * 192 + oc + unit] = H[r];
            } else {
                hW[pl * 2 + slot][unit] = (_Float16)H[r];
                if (cwEn) cWl[pl * 2 + slot][unit] = (_Float16)CN[r];
                if (TWO)  crW[r >> 1][r & 1] = (_Float16)CN[r];
            }
        }
    }
}

// ---- root (up, t=8): h7/c7 from par0 slot0; h9/c9 from par1 slot1 ----
__device__ __forceinline__ void root_level(
    const f16x8 (*bfr)[4], const f16x4* px,
    const _Float16 (*hR0)[68], const _Float16 (*cR0)[68],
    const _Float16 (*hR1)[68], const _Float16 (*cR1)[68],
    float* __restrict__ out, int pair0, int unit, int l15, int qd)
{
    f32x4 aio[3], aF7, aF9;
    #pragma unroll
    for (int r = 0; r < 4; ++r) {
        f16x4 g4 = px[r];
        aio[0][r] = (float)g4[0];
        aio[1][r] = (float)g4[1];
        aio[2][r] = (float)g4[2];
        aF7[r] = (float)g4[3];
        aF9[r] = (float)g4[3];
    }
    #pragma unroll
    for (int s = 0; s < 2; ++s) {
        f16x8 v7 = *(const f16x8*)&hR0[(l15 & 7) * 2 + 0][s * 32 + qd * 8];
        f16x8 v9 = *(const f16x8*)&hR1[(l15 & 7) * 2 + 1][s * 32 + qd * 8];
        f16x8 vs = v7 + v9;
        aio[0] = __builtin_amdgcn_mfma_f32_16x16x32_f16(vs, bfr[s][0], aio[0], 0, 0, 0);
        aio[1] = __builtin_amdgcn_mfma_f32_16x16x32_f16(vs, bfr[s][1], aio[1], 0, 0, 0);
        aio[2] = __builtin_amdgcn_mfma_f32_16x16x32_f16(vs, bfr[s][2], aio[2], 0, 0, 0);
        aF7 = __builtin_amdgcn_mfma_f32_16x16x32_f16(v7, bfr[s][3], aF7, 0, 0, 0);
        aF9 = __builtin_amdgcn_mfma_f32_16x16x32_f16(v9, bfr[s][3], aF9, 0, 0, 0);
    }
    f32x4 C7, C9;
    #pragma unroll
    for (int r = 0; r < 4; ++r) {
        int plc = (qd * 4 + r) & 7;
        C7[r] = (float)cR0[plc * 2 + 0][unit];
        C9[r] = (float)cR1[plc * 2 + 1][unit];
    }
    // cn = sigm(I)tanh(U) + sigm(F7)c7 + sigm(F9)c9, one rcp (vectorized):
    f32x4 EA = exp2v(aio[0]);
    f32x4 EO = exp2v(aio[1]);
    f32x4 EB = exp2v(aio[2]);
    f32x4 E7 = exp2v(aF7);
    f32x4 E9 = exp2v(aF9);
    f32x4 PQ  = (1.f + EA) * (1.f + EB);
    f32x4 S7  = 1.f + E7, S9 = 1.f + E9;
    f32x4 S79 = S7 * S9;
    f32x4 NUM = PQ * (C7 * S9 + C9 * S7) + (1.f - EB) * S79;
    f32x4 CN  = NUM * rcpv(PQ * S79);
    f32x4 EE  = exp2v(-N2K * CN);
    f32x4 H   = (1.f - EE) * rcpv((1.f + EE) * (1.f + EO));
    if (qd < 2) {
        #pragma unroll
        for (int r = 0; r < 4; ++r) {
            int pl = qd * 4 + r;
            out[(size_t)(pair0 + pl) * 192 + unit] = H[r];
        }
    }
}

__global__ __launch_bounds__(256, 5) void tree_kernel(
    const int* __restrict__ nb, const int* __restrict__ nt,
    const _Float16* __restrict__ XP, const _Float16* __restrict__ Upk,
    float* __restrict__ out)
{
    __shared__ _Float16 hS[2][2][NP * 2][68];  // [parity][dir][pl*2+slot][unit]
    __shared__ _Float16 cS[2][2][NP * 2][68];  // LDS c: only special levels
    __shared__ int btl[16][NP];                // byte offsets into XP rows

    const int tid = threadIdx.x, lane = tid & 63, w = tid >> 6;
    const int l15 = lane & 15, qd = lane >> 4;
    const int unit = w * 16 + l15;
    const int pair0 = blockIdx.x * NP;

    if (tid < 128) {
        int pos = tid >> 3, pl = tid & 7;
        int node = (pair0 + pl) * 16 + pos;
        btl[pos][pl] = (nb[node] * 512 + nt[node]) * 1024;
    }

    // hoist U fragments for both dirs (register-resident, 64 VGPRs)
    f16x8 bU[2][4], bD[2][4];
    #pragma unroll
    for (int s = 0; s < 2; ++s)
        #pragma unroll
        for (int g = 0; g < 4; ++g) {
            bU[s][g] = *(const f16x8*)(Upk + (g * 64 + unit) * 64 + s * 32 + qd * 8);
            bD[s][g] = *(const f16x8*)(Upk + 16384 + (g * 64 + unit) * 64 + s * 32 + qd * 8);
        }

    __syncthreads();   // btl visible

    const char* XPu = (const char*)XP;
    const char* XPdn = XPu + 512;

    // register c state: [parity][dir][r>>1] packed f16x2 (halves = slot)
    f16x2 creg[2][2][2] = {};

    // up-side ping-pong: level L consumed from pxu[L&1]; level t+1 issued
    // at t. Up level->positions: L<7: (L, 15-L); L==7: 7; L==8: 8 (root).
    // Down level->positions: L==0: 8; 1<=L<=7: (8-L, 8+L); L==8: 0.
    f16x4 pxu[2][4], pxd[4];
    gather_xp<1>(XPu, btl, 0, 15, unit, qd, pxu[0]);   // up L0

    #pragma unroll
    for (int t = 0; t < 9; ++t) {
        const int pt = t & 1, pw = pt ^ 1;
        // down side gather for THIS level (latency hides under up compute)
        if (t == 0)      gather_xp<0>(XPdn, btl, 8, 8, unit, qd, pxd);
        else if (t == 8) gather_xp<0>(XPdn, btl, 0, 0, unit, qd, pxd);
        else             gather_xp<1>(XPdn, btl, 8 - t, 8 + t, unit, qd, pxd);
        // up side gather for level t+1 (crosses the barrier)
        if (t < 6)       gather_xp<1>(XPu, btl, t + 1, 14 - t, unit, qd, pxu[pw]);
        else if (t == 6) gather_xp<0>(XPu, btl, 7, 7, unit, qd, pxu[pw]);
        else if (t == 7) gather_xp<0>(XPu, btl, 8, 8, unit, qd, pxu[pw]);

        // ---- up ----
        if (t < 7)
            side_level<1>(bU, pxu[pt], hS[pt][0], cS[pt][0],
                          hS[pw][0], cS[pw][0],
                          creg[pt][0], creg[pw][0],
                          (t >= 1) ? 1 : 0, (t == 6) ? 1 : 0,
                          out, pair0,
                          t ? 0 : -1, t ? 1 : -1, -1, -1, unit, l15, qd);
        else if (t == 7)
            side_level<0>(bU, pxu[pt], hS[pt][0], cS[pt][0],
                          hS[pw][0], cS[pw][0],
                          creg[pt][0], creg[pw][0], 0, 1,
                          out, pair0,
                          0, 0, -1, -1, unit, l15, qd);
        else
            root_level(bU, pxu[pt], hS[0][0], cS[0][0], hS[1][0], cS[1][0],
                       out, pair0, unit, l15, qd);

        // ---- down ----
        if (t == 0)
            side_level<0>(bD, pxd, hS[pt][1], cS[pt][1],
                          hS[pw][1], cS[pw][1],
                          creg[pt][1], creg[pw][1], 0, 1,
                          out, pair0,
                          -1, -1, -1, -1, unit, l15, qd);
        else if (t == 8)
            side_level<0>(bD, pxd, hS[pt][1], cS[pt][1],
                          hS[pw][1], cS[pw][1],
                          creg[pt][1], creg[pw][1], 0, 0,
                          out, pair0,
                          0, 0, 64, 64, unit, l15, qd);
        else
            side_level<1>(bD, pxd, hS[pt][1], cS[pt][1],
                          hS[pw][1], cS[pw][1],
                          creg[pt][1], creg[pw][1],
                          (t >= 2) ? 1 : 0, (t == 7) ? 1 : 0,
                          out, pair0,
                          0, (t == 1) ? 0 : 1, -1, (t == 7) ? 128 : -1,
                          unit, l15, qd);

        lgkm_barrier();   // LDS writes visible; global gathers stay in flight
    }
}

extern "C" void kernel_launch(void* const* d_in, const int* in_sizes, int n_in,
                              void* d_out, int out_size, void* d_ws, size_t ws_size,
                              hipStream_t stream)
{
    const float* tok  = (const float*)d_in[0];
    const float* ohp  = (const float*)d_in[1];
    const float* dep  = (const float*)d_in[2];
    const int*   nb   = (const int*)d_in[3];
    const int*   nt   = (const int*)d_in[4];
    const float* Wi_u = (const float*)d_in[13];
    const float* Ui_u = (const float*)d_in[14];
    const float* bi_u = (const float*)d_in[15];
    const float* Wf_u = (const float*)d_in[16];
    const float* Uf_u = (const float*)d_in[17];
    const float* bf_u = (const float*)d_in[18];
    const float* Wi_d = (const float*)d_in[19];
    const float* Ui_d = (const float*)d_in[20];
    const float* bi_d = (const float*)d_in[21];
    const float* Wf_d = (const float*)d_in[22];
    const float* Uf_d = (const float*)d_in[23];
    const float* bf_d = (const float*)d_in[24];

    char* ws = (char*)d_ws;
    _Float16* Bx  = (_Float16*)(ws);                    // 320 KB
    _Float16* Upk = (_Float16*)(ws + 0x50000);          // 64 KB
    float*    pb  = (float*)   (ws + 0x60000);          // 2 KB
    _Float16* XP  = (_Float16*)(ws + (12u << 20));      // 16 MB
    float* out = (float*)d_out;

    prep_kernel<<<768, 256, 0, stream>>>(Wi_u, Ui_u, bi_u, Wf_u, Uf_u, bf_u,
                                         Wi_d, Ui_d, bi_d, Wf_d, Uf_d, bf_d,
                                         Bx, Upk, pb);
    xp_gemm<<<1024, 256, 0, stream>>>(tok, ohp, dep, Bx, pb, XP);
    tree_kernel<<<2048, 256, 0, stream>>>(nb, nt, XP, Upk, out);

    (void)in_sizes; (void)n_in; (void)out_size; (void)ws_size;
}

// Round 9
// 184.800 us; speedup vs baseline: 1.5970x; 1.5970x over previous
//
#include <hip/hip_runtime.h>
#include <hip/hip_fp16.h>

// DepTreeLSTM on MI355X — R24 = exact revert to R21 (best timed: 185.0 µs,
// tree 65.1 µs). R23's occupancy restructure (NP=8, forced 5 waves/SIMD)
// spilled catastrophically (VGPR report 48 + 500MB scratch traffic/dispatch,
// tree 175 µs): register demand across the 9-level unrolled loop is
// irreducibly > the 102-VGPR 5-wave threshold. Occupancy is structurally
// 4 waves/SIMD; consolidating on the best-known kernel.
// Ledger: R16 exp2-gates (-6.7µs) | R17 down-prefetch FAIL | R18 ring-3
// (+1.4) | R19 down-prefetch FAIL | R20 c-reg (-1.7) | R21 pk-f32 (-3.0) |
// R22 setprio+trim neutral | R23 occupancy FAIL.
// prep: pack weights->fp16 (gate-interleaved, exp2-scaled), 768 blocks.
// xp_gemm: M=32 tiles / grid 1024, A staged from fp32 with cvt,
//   B via global_load_lds; XOR-8 granule swizzle.
// tree_kernel: 1024 blocks x 16 pairs, ping-pong LDS h state, creg c-state,
//   1 lgkm-only barrier/level, up-side XP prefetch 2 ahead, U frags hoisted.

typedef _Float16 f16x8 __attribute__((ext_vector_type(8)));
typedef _Float16 f16x4 __attribute__((ext_vector_type(4)));
typedef _Float16 f16x2 __attribute__((ext_vector_type(2)));
typedef float f32x4 __attribute__((ext_vector_type(4)));

#define NP 16   // pairs per tree block
#define N2K 2.8853900817779268f   // 2*log2(e); exp2(-N2K*x) = e^{-2x}

__device__ __forceinline__ void async16(const void* g, void* l) {
    __builtin_amdgcn_global_load_lds(
        (const __attribute__((address_space(1))) void*)g,
        (__attribute__((address_space(3))) void*)l, 16, 0, 0);
}
__device__ __forceinline__ void lgkm_barrier() {
    asm volatile("s_waitcnt lgkmcnt(0)\n\ts_barrier" ::: "memory");
}
__device__ __forceinline__ f32x4 exp2v(f32x4 x) {
    f32x4 y;
    y[0] = __builtin_amdgcn_exp2f(x[0]);
    y[1] = __builtin_amdgcn_exp2f(x[1]);
    y[2] = __builtin_amdgcn_exp2f(x[2]);
    y[3] = __builtin_amdgcn_exp2f(x[3]);
    return y;
}
__device__ __forceinline__ f32x4 rcpv(f32x4 x) {
    f32x4 y;
    y[0] = __builtin_amdgcn_rcpf(x[0]);
    y[1] = __builtin_amdgcn_rcpf(x[1]);
    y[2] = __builtin_amdgcn_rcpf(x[2]);
    y[3] = __builtin_amdgcn_rcpf(x[3]);
    return y;
}

// ---- prep: pack weights/bias to fp16, gate-interleaved cols, exp2-scaled ----
// Gate scale: I,O,F cols *= -log2e; U cols *= -2log2e. Applied identically to
// W (->Bx), U (->Upk) and b (->pb) so preacts land in exp2 domain:
//   sigm(x)  = 1/(1+exp2(x'))        x' = -log2e * x
//   tanh(u)  = (1-exp2(u'))/(1+exp2(u'))   u' = -2log2e * u
__global__ __launch_bounds__(256) void prep_kernel(
    const float* __restrict__ Wi_u, const float* __restrict__ Ui_u,
    const float* __restrict__ bi_u, const float* __restrict__ Wf_u,
    const float* __restrict__ Uf_u, const float* __restrict__ bf_u,
    const float* __restrict__ Wi_d, const float* __restrict__ Ui_d,
    const float* __restrict__ bi_d, const float* __restrict__ Wf_d,
    const float* __restrict__ Uf_d, const float* __restrict__ bf_d,
    _Float16* __restrict__ Bx, _Float16* __restrict__ Upk,
    float* __restrict__ pb)
{
    int idx = blockIdx.x * 256 + threadIdx.x;     // 196608 total
    if (idx < 512) {
        int d = idx >> 8, c = idx & 255, u = c >> 2, g = c & 3;
        const float* bio = d ? bi_d : bi_u;
        const float* bf  = d ? bf_d : bf_u;
        float s = (g == 2) ? -N2K : -0.5f * N2K;
        pb[idx] = s * ((g < 3) ? bio[g * 64 + u] : bf[u]);
    }
    if (idx < 163840) {                            // Bx: [dir][col256][k320]
        int d = idx / 81920, r1 = idx % 81920;
        int c = r1 / 320, k = r1 % 320, u = c >> 2, g = c & 3;
        const float* Wio = d ? Wi_d : Wi_u;
        const float* Wf  = d ? Wf_d : Wf_u;
        float s = (g == 2) ? -N2K : -0.5f * N2K;
        Bx[idx] = (_Float16)(s * ((g < 3) ? Wio[k * 192 + g * 64 + u]
                                          : Wf[k * 64 + u]));
    } else {                                       // Upk: 2*4*64*64
        int j = idx - 163840;
        int d = j >> 14, r2 = j & 16383;
        int g = r2 >> 12, u = (r2 >> 6) & 63, k = r2 & 63;
        const float* Uio = d ? Ui_d : Ui_u;
        const float* Uf  = d ? Uf_d : Uf_u;
        float s = (g == 2) ? -N2K : -0.5f * N2K;
        Upk[j] = (_Float16)(s * ((g < 3) ? Uio[k * 192 + g * 64 + u]
                                         : Uf[k * 64 + u]));
    }
}

// ---- XP = [tok|oh|dep] @ Bx + pb : M=32 tiles, K=320, N=256; grid 1024 ----
__global__ __launch_bounds__(256, 2) void xp_gemm(
    const float* __restrict__ tok, const float* __restrict__ oh,
    const float* __restrict__ dep,
    const _Float16* __restrict__ Bx, const float* __restrict__ pb,
    _Float16* __restrict__ XP)
{
    __shared__ _Float16 At[32 * 64];      // 4 KB
    __shared__ _Float16 Btl[256 * 64];    // 32 KB
    const int dir = blockIdx.x & 1, mt = blockIdx.x >> 1;
    const int tid = threadIdx.x, lane = tid & 63, w = tid >> 6;
    const int l15 = lane & 15, qd = lane >> 4;
    const int rsub = lane >> 3, pg = lane & 7;
    const int kg = (pg - rsub) & 7;                  // logical granule in tile
    const int koff = kg * 8;
    const int rowbase = mt * 32;
    const _Float16* Bb = Bx + (size_t)dir * 81920 + (w * 64 + rsub) * 320 + koff;

    f32x4 acc[2][4];
    #pragma unroll
    for (int i = 0; i < 2; ++i)
        #pragma unroll
        for (int j = 0; j < 4; ++j) acc[i][j] = (f32x4){0.f, 0.f, 0.f, 0.f};

    #pragma unroll
    for (int kt = 0; kt < 5; ++kt) {
        // ---- A stage: fp32 source -> cvt -> swizzled LDS (1 row/lane) ----
        {
            int row = rowbase + w * 8 + rsub;              // bt index
            int g = kt * 8 + kg;                           // granule 0..39
            const float* src = (g < 32) ? tok + (size_t)row * 256 + g * 8
                             : (g < 36) ? oh  + (size_t)row * 32 + (g - 32) * 8
                                        : dep + (size_t)row * 32 + (g - 36) * 8;
            float4 f0 = *(const float4*)src;
            float4 f1 = *(const float4*)(src + 4);
            f16x8 v;
            v[0] = (_Float16)f0.x; v[1] = (_Float16)f0.y;
            v[2] = (_Float16)f0.z; v[3] = (_Float16)f0.w;
            v[4] = (_Float16)f1.x; v[5] = (_Float16)f1.y;
            v[6] = (_Float16)f1.z; v[7] = (_Float16)f1.w;
            *(f16x8*)&At[(w * 8 + rsub) * 64 + pg * 8] = v;
        }
        // ---- B stage: async16 from packed Bx ----
        #pragma unroll
        for (int is = 0; is < 8; ++is)
            async16(Bb + (size_t)is * 8 * 320 + kt * 64,
                    &Btl[(w * 64 + is * 8) * 64]);
        __syncthreads();
        #pragma unroll
        for (int s = 0; s < 2; ++s) {
            const int g0 = s * 4 + qd;
            f16x8 af[2];
            #pragma unroll
            for (int i = 0; i < 2; ++i) {
                int R = i * 16 + l15;
                af[i] = *(const f16x8*)&At[R * 64 + ((g0 + R) & 7) * 8];
            }
            #pragma unroll
            for (int j = 0; j < 4; ++j) {
                int C = j * 64 + w * 16 + l15;
                f16x8 bf = *(const f16x8*)&Btl[C * 64 + ((g0 + C) & 7) * 8];
                #pragma unroll
                for (int i = 0; i < 2; ++i)
                    acc[i][j] = __builtin_amdgcn_mfma_f32_16x16x32_f16(
                        af[i], bf, acc[i][j], 0, 0, 0);
            }
        }
        __syncthreads();
    }
    #pragma unroll
    for (int i = 0; i < 2; ++i)
        #pragma unroll
        for (int j = 0; j < 4; ++j) {
            int colp = j * 64 + w * 16 + l15;
            float bias = pb[dir * 256 + colp];
            #pragma unroll
            for (int r = 0; r < 4; ++r) {
                int row = rowbase + i * 16 + qd * 4 + r;
                XP[(size_t)row * 512 + dir * 256 + colp] =
                    (_Float16)(acc[i][j][r] + bias);
            }
        }
}

// ---- gather XP preacts for one side of one level into registers ----
template<int RPP>
__device__ __forceinline__ void gather_xp(
    const char* __restrict__ XPd, const int (*btl)[NP],
    int p0, int p1, int unit, int qd, f16x4* px)
{
    #pragma unroll
    for (int i = 0; i < RPP; ++i)
        #pragma unroll
        for (int r = 0; r < 4; ++r) {
            int row = i * 16 + qd * 4 + r;
            int pl  = (RPP == 2) ? (row >> 1) : row;
            int pos = (RPP == 2) ? ((row & 1) ? p1 : p0) : p0;
            px[i * 4 + r] = *(const f16x4*)(XPd + btl[pos][pl] + unit * 8);
        }
}

// ---- compute one side of one level (state read parity -> write parity) ----
// Preacts arrive exp2-scaled (see prep_kernel). Cell update with shared rcp:
//   a=2^I', b=2^U', c=2^F';  cn = [(1-b)(1+c) + cin(1+a)(1+b)]
//                                 / [(1+a)(1+b)(1+c)]
//   e=2^{-N2K*cn}, o=2^O';   h  = (1-e) / [(1+e)(1+o)]
// Epilogue arithmetic is whole-f32x4 over r so the backend emits packed
// v_pk_*_f32 pairs; exp2/rcp stay scalar (bit-exact vs scalar form).
// c state: RPP=2 cells are thread-local across levels -> packed f16x2 regs
// (crR/crW, idx i*2+(r>>1), half = slot). cregr: read c from regs. cwEn:
// mirror c to LDS (next consumer is an RPP=1/root level, cross-mapped).
template<int RPP>
__device__ __forceinline__ void side_level(
    const f16x8 (*bfr)[4], const f16x4* px,
    const _Float16 (*hR)[68], const _Float16 (*cR)[68],
    _Float16 (*hW)[68], _Float16 (*cWl)[68],
    f16x2* crR, f16x2* crW, int cregr, int cwEn,
    float* __restrict__ out, int pair0,
    int rs0, int rs1, int oc0, int oc1,
    int unit, int l15, int qd)
{
    f32x4 acc[RPP][4];
    #pragma unroll
    for (int i = 0; i < RPP; ++i)
        #pragma unroll
        for (int r = 0; r < 4; ++r) {
            f16x4 g4 = px[i * 4 + r];
            acc[i][0][r] = (float)g4[0];
            acc[i][1][r] = (float)g4[1];
            acc[i][2][r] = (float)g4[2];
            acc[i][3][r] = (float)g4[3];
        }

    if (rs0 >= 0) {
        #pragma unroll
        for (int s = 0; s < 2; ++s)
            #pragma unroll
            for (int i = 0; i < RPP; ++i) {
                int R = i * 16 + l15;
                int arow = (RPP == 2) ? ((R & ~1) | ((R & 1) ? rs1 : rs0))
                                      : (R * 2 + rs0);
                f16x8 af = *(const f16x8*)&hR[arow][s * 32 + qd * 8];
                #pragma unroll
                for (int g = 0; g < 4; ++g)
                    acc[i][g] = __builtin_amdgcn_mfma_f32_16x16x32_f16(
                        af, bfr[s][g], acc[i][g], 0, 0, 0);
            }
    }

    #pragma unroll
    for (int i = 0; i < RPP; ++i) {
        // gather cin as a vector
        f32x4 CIN;
        #pragma unroll
        for (int r = 0; r < 4; ++r) {
            int row = i * 16 + qd * 4 + r;
            int pl   = (RPP == 2) ? (row >> 1) : row;
            int slot = (RPP == 2) ? (row & 1) : 0;
            int rs = slot ? rs1 : rs0;
            if (RPP == 2 && cregr)
                CIN[r] = (float)crR[i * 2 + (r >> 1)][rs];
            else
                CIN[r] = (rs >= 0) ? (float)cR[pl * 2 + rs][unit] : 0.f;
        }
        f32x4 EA = exp2v(acc[i][0]);            // e^{-I}
        f32x4 EO = exp2v(acc[i][1]);            // e^{-O}
        f32x4 EB = exp2v(acc[i][2]);            // e^{-2U}
        f32x4 EC = exp2v(acc[i][3]);            // e^{-F}
        f32x4 PQ = (1.f + EA) * (1.f + EB);
        f32x4 PC = 1.f + EC;
        f32x4 NUM = CIN * PQ + (1.f - EB) * PC;
        f32x4 CN = NUM * rcpv(PQ * PC);
        f32x4 EE = exp2v(-N2K * CN);            // e^{-2cn}
        f32x4 H = (1.f - EE) * rcpv((1.f + EE) * (1.f + EO));
        #pragma unroll
        for (int r = 0; r < 4; ++r) {
            int row = i * 16 + qd * 4 + r;
            int pl   = (RPP == 2) ? (row >> 1) : row;
            int slot = (RPP == 2) ? (row & 1) : 0;
            int oc = slot ? oc1 : oc0;
            if (oc >= 0) {
                out[(size_t)(pair0 + pl) * 192 + oc + unit] = H[r];
            } else {
                hW[pl * 2 + slot][unit] = (_Float16)H[r];
                if (cwEn) cWl[pl * 2 + slot][unit] = (_Float16)CN[r];
                if (RPP == 2) crW[i * 2 + (r >> 1)][r & 1] = (_Float16)CN[r];
            }
        }
    }
}

// ---- root (up, t=8): h7/c7 from par0 slot0; h9/c9 from par1 slot1 ----
__device__ __forceinline__ void root_level(
    const f16x8 (*bfr)[4], const f16x4* px,
    const _Float16 (*hR0)[68], const _Float16 (*cR0)[68],
    const _Float16 (*hR1)[68], const _Float16 (*cR1)[68],
    float* __restrict__ out, int pair0, int unit, int l15, int qd)
{
    f32x4 aio[3], aF7, aF9;
    #pragma unroll
    for (int r = 0; r < 4; ++r) {
        f16x4 g4 = px[r];
        aio[0][r] = (float)g4[0];
        aio[1][r] = (float)g4[1];
        aio[2][r] = (float)g4[2];
        aF7[r] = (float)g4[3];
        aF9[r] = (float)g4[3];
    }
    #pragma unroll
    for (int s = 0; s < 2; ++s) {
        f16x8 v7 = *(const f16x8*)&hR0[l15 * 2 + 0][s * 32 + qd * 8];
        f16x8 v9 = *(const f16x8*)&hR1[l15 * 2 + 1][s * 32 + qd * 8];
        f16x8 vs = v7 + v9;
        aio[0] = __builtin_amdgcn_mfma_f32_16x16x32_f16(vs, bfr[s][0], aio[0], 0, 0, 0);
        aio[1] = __builtin_amdgcn_mfma_f32_16x16x32_f16(vs, bfr[s][1], aio[1], 0, 0, 0);
        aio[2] = __builtin_amdgcn_mfma_f32_16x16x32_f16(vs, bfr[s][2], aio[2], 0, 0, 0);
        aF7 = __builtin_amdgcn_mfma_f32_16x16x32_f16(v7, bfr[s][3], aF7, 0, 0, 0);
        aF9 = __builtin_amdgcn_mfma_f32_16x16x32_f16(v9, bfr[s][3], aF9, 0, 0, 0);
    }
    f32x4 C7, C9;
    #pragma unroll
    for (int r = 0; r < 4; ++r) {
        int pl = qd * 4 + r;
        C7[r] = (float)cR0[pl * 2 + 0][unit];
        C9[r] = (float)cR1[pl * 2 + 1][unit];
    }
    // cn = sigm(I)tanh(U) + sigm(F7)c7 + sigm(F9)c9, one rcp (vectorized):
    f32x4 EA = exp2v(aio[0]);
    f32x4 EO = exp2v(aio[1]);
    f32x4 EB = exp2v(aio[2]);
    f32x4 E7 = exp2v(aF7);
    f32x4 E9 = exp2v(aF9);
    f32x4 PQ  = (1.f + EA) * (1.f + EB);
    f32x4 S7  = 1.f + E7, S9 = 1.f + E9;
    f32x4 S79 = S7 * S9;
    f32x4 NUM = PQ * (C7 * S9 + C9 * S7) + (1.f - EB) * S79;
    f32x4 CN  = NUM * rcpv(PQ * S79);
    f32x4 EE  = exp2v(-N2K * CN);
    f32x4 H   = (1.f - EE) * rcpv((1.f + EE) * (1.f + EO));
    #pragma unroll
    for (int r = 0; r < 4; ++r) {
        int pl = qd * 4 + r;
        out[(size_t)(pair0 + pl) * 192 + unit] = H[r];
    }
}

__global__ __launch_bounds__(256, 2) void tree_kernel(
    const int* __restrict__ nb, const int* __restrict__ nt,
    const _Float16* __restrict__ XP, const _Float16* __restrict__ Upk,
    float* __restrict__ out)
{
    __shared__ _Float16 hS[2][2][NP * 2][68];  // [parity][dir][pl*2+slot][unit]
    __shared__ _Float16 cS[2][2][NP * 2][68];  // LDS c: only special levels
    __shared__ int btl[16][NP];                // byte offsets into XP rows

    const int tid = threadIdx.x, lane = tid & 63, w = tid >> 6;
    const int l15 = lane & 15, qd = lane >> 4;
    const int unit = w * 16 + l15;
    const int pair0 = blockIdx.x * NP;

    {
        int pos = tid >> 4, pl = tid & 15;
        int node = (pair0 + pl) * 16 + pos;
        btl[pos][pl] = (nb[node] * 512 + nt[node]) * 1024;
    }

    // hoist U fragments for both dirs (register-resident, 64 VGPRs)
    f16x8 bU[2][4], bD[2][4];
    #pragma unroll
    for (int s = 0; s < 2; ++s)
        #pragma unroll
        for (int g = 0; g < 4; ++g) {
            bU[s][g] = *(const f16x8*)(Upk + (g * 64 + unit) * 64 + s * 32 + qd * 8);
            bD[s][g] = *(const f16x8*)(Upk + 16384 + (g * 64 + unit) * 64 + s * 32 + qd * 8);
        }

    __syncthreads();   // btl visible

    const char* XPu = (const char*)XP;
    const char* XPdn = XPu + 512;

    // register c state: [parity][dir][i*2+p] packed f16x2 (halves = slot)
    f16x2 creg[2][2][4] = {};

    // up-side ring-3: level L consumed from pxu[L%3]; level t+2 issued at t.
    // Up level->positions: L<7: (L, 15-L); L==7: 7; L==8: 8 (root).
    f16x4 pxu[3][8], pxd[8];
    gather_xp<2>(XPu, btl, 0, 15, unit, qd, pxu[0]);   // up L0
    gather_xp<2>(XPu, btl, 1, 14, unit, qd, pxu[1]);   // up L1

    #pragma unroll
    for (int t = 0; t < 9; ++t) {
        const int pt = t & 1, pw = pt ^ 1;
        const int cur = t % 3, nx2 = (t + 2) % 3;
        // down side gather for THIS level (R18 known-good schedule; latency
        // hides under the up-side compute below)
        if (t == 0)      gather_xp<1>(XPdn, btl, 8, 8, unit, qd, pxd);
        else if (t == 8) gather_xp<1>(XPdn, btl, 0, 0, unit, qd, pxd);
        else             gather_xp<2>(XPdn, btl, 8 - t, 8 + t, unit, qd, pxd);
        // up side gather for level t+2 (two levels / two barriers ahead)
        if (t < 5)       gather_xp<2>(XPu, btl, t + 2, 13 - t, unit, qd, pxu[nx2]);
        else if (t == 5) gather_xp<1>(XPu, btl, 7, 7, unit, qd, pxu[nx2]);
        else if (t == 6) gather_xp<1>(XPu, btl, 8, 8, unit, qd, pxu[nx2]);

        // ---- up ----
        if (t < 7)
            side_level<2>(bU, pxu[cur], hS[pt][0], cS[pt][0],
                          hS[pw][0], cS[pw][0],
                          creg[pt][0], creg[pw][0],
                          (t >= 1) ? 1 : 0, (t == 6) ? 1 : 0,
                          out, pair0,
                          t ? 0 : -1, t ? 1 : -1, -1, -1, unit, l15, qd);
        else if (t == 7)
            side_level<1>(bU, pxu[cur], hS[pt][0], cS[pt][0],
                          hS[pw][0], cS[pw][0],
                          creg[pt][0], creg[pw][0], 0, 1,
                          out, pair0,
                          0, 0, -1, -1, unit, l15, qd);
        else
            root_level(bU, pxu[cur], hS[0][0], cS[0][0], hS[1][0], cS[1][0],
                       out, pair0, unit, l15, qd);

        // ---- down ----
        if (t == 0)
            side_level<1>(bD, pxd, hS[pt][1], cS[pt][1],
                          hS[pw][1], cS[pw][1],
                          creg[pt][1], creg[pw][1], 0, 1,
                          out, pair0,
                          -1, -1, -1, -1, unit, l15, qd);
        else if (t == 8)
            side_level<1>(bD, pxd, hS[pt][1], cS[pt][1],
                          hS[pw][1], cS[pw][1],
                          creg[pt][1], creg[pw][1], 0, 0,
                          out, pair0,
                          0, 0, 64, 64, unit, l15, qd);
        else
            side_level<2>(bD, pxd, hS[pt][1], cS[pt][1],
                          hS[pw][1], cS[pw][1],
                          creg[pt][1], creg[pw][1],
                          (t >= 2) ? 1 : 0, (t == 7) ? 1 : 0,
                          out, pair0,
                          0, (t == 1) ? 0 : 1, -1, (t == 7) ? 128 : -1,
                          unit, l15, qd);

        lgkm_barrier();   // LDS writes visible; global gathers stay in flight
    }
}

extern "C" void kernel_launch(void* const* d_in, const int* in_sizes, int n_in,
                              void* d_out, int out_size, void* d_ws, size_t ws_size,
                              hipStream_t stream)
{
    const float* tok  = (const float*)d_in[0];
    const float* ohp  = (const float*)d_in[1];
    const float* dep  = (const float*)d_in[2];
    const int*   nb   = (const int*)d_in[3];
    const int*   nt   = (const int*)d_in[4];
    const float* Wi_u = (const float*)d_in[13];
    const float* Ui_u = (const float*)d_in[14];
    const float* bi_u = (const float*)d_in[15];
    const float* Wf_u = (const float*)d_in[16];
    const float* Uf_u = (const float*)d_in[17];
    const float* bf_u = (const float*)d_in[18];
    const float* Wi_d = (const float*)d_in[19];
    const float* Ui_d = (const float*)d_in[20];
    const float* bi_d = (const float*)d_in[21];
    const float* Wf_d = (const float*)d_in[22];
    const float* Uf_d = (const float*)d_in[23];
    const float* bf_d = (const float*)d_in[24];

    char* ws = (char*)d_ws;
    _Float16* Bx  = (_Float16*)(ws);                    // 320 KB
    _Float16* Upk = (_Float16*)(ws + 0x50000);          // 64 KB
    float*    pb  = (float*)   (ws + 0x60000);          // 2 KB
    _Float16* XP  = (_Float16*)(ws + (12u << 20));      // 16 MB
    float* out = (float*)d_out;

    prep_kernel<<<768, 256, 0, stream>>>(Wi_u, Ui_u, bi_u, Wf_u, Uf_u, bf_u,
                                         Wi_d, Ui_d, bi_d, Wf_d, Uf_d, bf_d,
                                         Bx, Upk, pb);
    xp_gemm<<<1024, 256, 0, stream>>>(tok, ohp, dep, Bx, pb, XP);
    tree_kernel<<<1024, 256, 0, stream>>>(nb, nt, XP, Upk, out);

    (void)in_sizes; (void)n_in; (void)out_size; (void)ws_size;
}

// Round 10
// 176.545 us; speedup vs baseline: 1.6717x; 1.0468x over previous
//
#include <hip/hip_runtime.h>
#include <hip/hip_fp16.h>

// DepTreeLSTM on MI355X — R25: side-split tree kernel. Up and down LSTM
// recurrences are independent (disjoint state/XP-halves/out-columns), so run
// them in SEPARATE BLOCKS of one dispatch: grid 2048, side=blockIdx&1.
// Each block carries HALF the register/LDS demand of R24's combined kernel
// (one U-frag set 32v, one ping-pong prefetch 32v, one creg 8v, LDS 18.4KB)
// -> allocator should land ~90 VGPR -> 5-6 blocks/CU naturally (no forced
// launch_bounds cap — R23's spill mode structurally avoided). Down side gets
// cross-barrier prefetch (R17 schedule) which is now load-bearing.
// Bet: +25-50% co-resident barrier domains beats 2x per-work barrier count.
// Decision: VGPR<=102 & tree<62 = win; VGPR>=108 or spill -> revert R24.
// Ledger: R16 exp2 (-6.7) | R17 FAIL | R18 ring3 (+1.4) | R19 FAIL |
// R20 c-reg (-1.7) | R21 pk-f32 (-3.0) | R22 neutral | R23 FAIL | R24 best.
// prep: pack weights->fp16 (gate-interleaved, exp2-scaled), 768 blocks.
// xp_gemm: M=32 tiles / grid 1024, A staged from fp32 with cvt,
//   B via global_load_lds; XOR-8 granule swizzle.

typedef _Float16 f16x8 __attribute__((ext_vector_type(8)));
typedef _Float16 f16x4 __attribute__((ext_vector_type(4)));
typedef _Float16 f16x2 __attribute__((ext_vector_type(2)));
typedef float f32x4 __attribute__((ext_vector_type(4)));

#define NP 16   // pairs per tree block
#define N2K 2.8853900817779268f   // 2*log2(e); exp2(-N2K*x) = e^{-2x}

__device__ __forceinline__ void async16(const void* g, void* l) {
    __builtin_amdgcn_global_load_lds(
        (const __attribute__((address_space(1))) void*)g,
        (__attribute__((address_space(3))) void*)l, 16, 0, 0);
}
__device__ __forceinline__ void lgkm_barrier() {
    asm volatile("s_waitcnt lgkmcnt(0)\n\ts_barrier" ::: "memory");
}
__device__ __forceinline__ f32x4 exp2v(f32x4 x) {
    f32x4 y;
    y[0] = __builtin_amdgcn_exp2f(x[0]);
    y[1] = __builtin_amdgcn_exp2f(x[1]);
    y[2] = __builtin_amdgcn_exp2f(x[2]);
    y[3] = __builtin_amdgcn_exp2f(x[3]);
    return y;
}
__device__ __forceinline__ f32x4 rcpv(f32x4 x) {
    f32x4 y;
    y[0] = __builtin_amdgcn_rcpf(x[0]);
    y[1] = __builtin_amdgcn_rcpf(x[1]);
    y[2] = __builtin_amdgcn_rcpf(x[2]);
    y[3] = __builtin_amdgcn_rcpf(x[3]);
    return y;
}

// ---- prep: pack weights/bias to fp16, gate-interleaved cols, exp2-scaled ----
// Gate scale: I,O,F cols *= -log2e; U cols *= -2log2e. Applied identically to
// W (->Bx), U (->Upk) and b (->pb) so preacts land in exp2 domain:
//   sigm(x)  = 1/(1+exp2(x'))        x' = -log2e * x
//   tanh(u)  = (1-exp2(u'))/(1+exp2(u'))   u' = -2log2e * u
__global__ __launch_bounds__(256) void prep_kernel(
    const float* __restrict__ Wi_u, const float* __restrict__ Ui_u,
    const float* __restrict__ bi_u, const float* __restrict__ Wf_u,
    const float* __restrict__ Uf_u, const float* __restrict__ bf_u,
    const float* __restrict__ Wi_d, const float* __restrict__ Ui_d,
    const float* __restrict__ bi_d, const float* __restrict__ Wf_d,
    const float* __restrict__ Uf_d, const float* __restrict__ bf_d,
    _Float16* __restrict__ Bx, _Float16* __restrict__ Upk,
    float* __restrict__ pb)
{
    int idx = blockIdx.x * 256 + threadIdx.x;     // 196608 total
    if (idx < 512) {
        int d = idx >> 8, c = idx & 255, u = c >> 2, g = c & 3;
        const float* bio = d ? bi_d : bi_u;
        const float* bf  = d ? bf_d : bf_u;
        float s = (g == 2) ? -N2K : -0.5f * N2K;
        pb[idx] = s * ((g < 3) ? bio[g * 64 + u] : bf[u]);
    }
    if (idx < 163840) {                            // Bx: [dir][col256][k320]
        int d = idx / 81920, r1 = idx % 81920;
        int c = r1 / 320, k = r1 % 320, u = c >> 2, g = c & 3;
        const float* Wio = d ? Wi_d : Wi_u;
        const float* Wf  = d ? Wf_d : Wf_u;
        float s = (g == 2) ? -N2K : -0.5f * N2K;
        Bx[idx] = (_Float16)(s * ((g < 3) ? Wio[k * 192 + g * 64 + u]
                                          : Wf[k * 64 + u]));
    } else {                                       // Upk: 2*4*64*64
        int j = idx - 163840;
        int d = j >> 14, r2 = j & 16383;
        int g = r2 >> 12, u = (r2 >> 6) & 63, k = r2 & 63;
        const float* Uio = d ? Ui_d : Ui_u;
        const float* Uf  = d ? Uf_d : Uf_u;
        float s = (g == 2) ? -N2K : -0.5f * N2K;
        Upk[j] = (_Float16)(s * ((g < 3) ? Uio[k * 192 + g * 64 + u]
                                         : Uf[k * 64 + u]));
    }
}

// ---- XP = [tok|oh|dep] @ Bx + pb : M=32 tiles, K=320, N=256; grid 1024 ----
__global__ __launch_bounds__(256, 2) void xp_gemm(
    const float* __restrict__ tok, const float* __restrict__ oh,
    const float* __restrict__ dep,
    const _Float16* __restrict__ Bx, const float* __restrict__ pb,
    _Float16* __restrict__ XP)
{
    __shared__ _Float16 At[32 * 64];      // 4 KB
    __shared__ _Float16 Btl[256 * 64];    // 32 KB
    const int dir = blockIdx.x & 1, mt = blockIdx.x >> 1;
    const int tid = threadIdx.x, lane = tid & 63, w = tid >> 6;
    const int l15 = lane & 15, qd = lane >> 4;
    const int rsub = lane >> 3, pg = lane & 7;
    const int kg = (pg - rsub) & 7;                  // logical granule in tile
    const int koff = kg * 8;
    const int rowbase = mt * 32;
    const _Float16* Bb = Bx + (size_t)dir * 81920 + (w * 64 + rsub) * 320 + koff;

    f32x4 acc[2][4];
    #pragma unroll
    for (int i = 0; i < 2; ++i)
        #pragma unroll
        for (int j = 0; j < 4; ++j) acc[i][j] = (f32x4){0.f, 0.f, 0.f, 0.f};

    #pragma unroll
    for (int kt = 0; kt < 5; ++kt) {
        // ---- A stage: fp32 source -> cvt -> swizzled LDS (1 row/lane) ----
        {
            int row = rowbase + w * 8 + rsub;              // bt index
            int g = kt * 8 + kg;                           // granule 0..39
            const float* src = (g < 32) ? tok + (size_t)row * 256 + g * 8
                             : (g < 36) ? oh  + (size_t)row * 32 + (g - 32) * 8
                                        : dep + (size_t)row * 32 + (g - 36) * 8;
            float4 f0 = *(const float4*)src;
            float4 f1 = *(const float4*)(src + 4);
            f16x8 v;
            v[0] = (_Float16)f0.x; v[1] = (_Float16)f0.y;
            v[2] = (_Float16)f0.z; v[3] = (_Float16)f0.w;
            v[4] = (_Float16)f1.x; v[5] = (_Float16)f1.y;
            v[6] = (_Float16)f1.z; v[7] = (_Float16)f1.w;
            *(f16x8*)&At[(w * 8 + rsub) * 64 + pg * 8] = v;
        }
        // ---- B stage: async16 from packed Bx ----
        #pragma unroll
        for (int is = 0; is < 8; ++is)
            async16(Bb + (size_t)is * 8 * 320 + kt * 64,
                    &Btl[(w * 64 + is * 8) * 64]);
        __syncthreads();
        #pragma unroll
        for (int s = 0; s < 2; ++s) {
            const int g0 = s * 4 + qd;
            f16x8 af[2];
            #pragma unroll
            for (int i = 0; i < 2; ++i) {
                int R = i * 16 + l15;
                af[i] = *(const f16x8*)&At[R * 64 + ((g0 + R) & 7) * 8];
            }
            #pragma unroll
            for (int j = 0; j < 4; ++j) {
                int C = j * 64 + w * 16 + l15;
                f16x8 bf = *(const f16x8*)&Btl[C * 64 + ((g0 + C) & 7) * 8];
                #pragma unroll
                for (int i = 0; i < 2; ++i)
                    acc[i][j] = __builtin_amdgcn_mfma_f32_16x16x32_f16(
                        af[i], bf, acc[i][j], 0, 0, 0);
            }
        }
        __syncthreads();
    }
    #pragma unroll
    for (int i = 0; i < 2; ++i)
        #pragma unroll
        for (int j = 0; j < 4; ++j) {
            int colp = j * 64 + w * 16 + l15;
            float bias = pb[dir * 256 + colp];
            #pragma unroll
            for (int r = 0; r < 4; ++r) {
                int row = rowbase + i * 16 + qd * 4 + r;
                XP[(size_t)row * 512 + dir * 256 + colp] =
                    (_Float16)(acc[i][j][r] + bias);
            }
        }
}

// ---- gather XP preacts for one side of one level into registers ----
template<int RPP>
__device__ __forceinline__ void gather_xp(
    const char* __restrict__ XPd, const int (*btl)[NP],
    int p0, int p1, int unit, int qd, f16x4* px)
{
    #pragma unroll
    for (int i = 0; i < RPP; ++i)
        #pragma unroll
        for (int r = 0; r < 4; ++r) {
            int row = i * 16 + qd * 4 + r;
            int pl  = (RPP == 2) ? (row >> 1) : row;
            int pos = (RPP == 2) ? ((row & 1) ? p1 : p0) : p0;
            px[i * 4 + r] = *(const f16x4*)(XPd + btl[pos][pl] + unit * 8);
        }
}

// ---- compute one level of one side (state read parity -> write parity) ----
// Preacts arrive exp2-scaled (see prep_kernel). Cell update with shared rcp:
//   a=2^I', b=2^U', c=2^F';  cn = [(1-b)(1+c) + cin(1+a)(1+b)]
//                                 / [(1+a)(1+b)(1+c)]
//   e=2^{-N2K*cn}, o=2^O';   h  = (1-e) / [(1+e)(1+o)]
// Epilogue arithmetic is whole-f32x4 over r -> packed v_pk_*_f32 pairs;
// exp2/rcp scalar per element (bit-exact vs scalar form).
// c state: RPP=2 cells are thread-local across levels -> packed f16x2 regs
// (crR/crW, idx i*2+(r>>1), half = slot). cregr: read c from regs. cwEn:
// mirror c to LDS (next consumer is an RPP=1/root level, cross-mapped).
template<int RPP>
__device__ __forceinline__ void side_level(
    const f16x8 (*bfr)[4], const f16x4* px,
    const _Float16 (*hR)[68], const _Float16 (*cR)[68],
    _Float16 (*hW)[68], _Float16 (*cWl)[68],
    f16x2* crR, f16x2* crW, int cregr, int cwEn,
    float* __restrict__ out, int pair0,
    int rs0, int rs1, int oc0, int oc1,
    int unit, int l15, int qd)
{
    f32x4 acc[RPP][4];
    #pragma unroll
    for (int i = 0; i < RPP; ++i)
        #pragma unroll
        for (int r = 0; r < 4; ++r) {
            f16x4 g4 = px[i * 4 + r];
            acc[i][0][r] = (float)g4[0];
            acc[i][1][r] = (float)g4[1];
            acc[i][2][r] = (float)g4[2];
            acc[i][3][r] = (float)g4[3];
        }

    if (rs0 >= 0) {
        #pragma unroll
        for (int s = 0; s < 2; ++s)
            #pragma unroll
            for (int i = 0; i < RPP; ++i) {
                int R = i * 16 + l15;
                int arow = (RPP == 2) ? ((R & ~1) | ((R & 1) ? rs1 : rs0))
                                      : (R * 2 + rs0);
                f16x8 af = *(const f16x8*)&hR[arow][s * 32 + qd * 8];
                #pragma unroll
                for (int g = 0; g < 4; ++g)
                    acc[i][g] = __builtin_amdgcn_mfma_f32_16x16x32_f16(
                        af, bfr[s][g], acc[i][g], 0, 0, 0);
            }
    }

    #pragma unroll
    for (int i = 0; i < RPP; ++i) {
        // gather cin as a vector
        f32x4 CIN;
        #pragma unroll
        for (int r = 0; r < 4; ++r) {
            int row = i * 16 + qd * 4 + r;
            int pl   = (RPP == 2) ? (row >> 1) : row;
            int slot = (RPP == 2) ? (row & 1) : 0;
            int rs = slot ? rs1 : rs0;
            if (RPP == 2 && cregr)
                CIN[r] = (float)crR[i * 2 + (r >> 1)][rs];
            else
                CIN[r] = (rs >= 0) ? (float)cR[pl * 2 + rs][unit] : 0.f;
        }
        f32x4 EA = exp2v(acc[i][0]);            // e^{-I}
        f32x4 EO = exp2v(acc[i][1]);            // e^{-O}
        f32x4 EB = exp2v(acc[i][2]);            // e^{-2U}
        f32x4 EC = exp2v(acc[i][3]);            // e^{-F}
        f32x4 PQ = (1.f + EA) * (1.f + EB);
        f32x4 PC = 1.f + EC;
        f32x4 NUM = CIN * PQ + (1.f - EB) * PC;
        f32x4 CN = NUM * rcpv(PQ * PC);
        f32x4 EE = exp2v(-N2K * CN);            // e^{-2cn}
        f32x4 H = (1.f - EE) * rcpv((1.f + EE) * (1.f + EO));
        #pragma unroll
        for (int r = 0; r < 4; ++r) {
            int row = i * 16 + qd * 4 + r;
            int pl   = (RPP == 2) ? (row >> 1) : row;
            int slot = (RPP == 2) ? (row & 1) : 0;
            int oc = slot ? oc1 : oc0;
            if (oc >= 0) {
                out[(size_t)(pair0 + pl) * 192 + oc + unit] = H[r];
            } else {
                hW[pl * 2 + slot][unit] = (_Float16)H[r];
                if (cwEn) cWl[pl * 2 + slot][unit] = (_Float16)CN[r];
                if (RPP == 2) crW[i * 2 + (r >> 1)][r & 1] = (_Float16)CN[r];
            }
        }
    }
}

// ---- root (up, t=8): h7/c7 from par0 slot0; h9/c9 from par1 slot1 ----
__device__ __forceinline__ void root_level(
    const f16x8 (*bfr)[4], const f16x4* px,
    const _Float16 (*hR0)[68], const _Float16 (*cR0)[68],
    const _Float16 (*hR1)[68], const _Float16 (*cR1)[68],
    float* __restrict__ out, int pair0, int unit, int l15, int qd)
{
    f32x4 aio[3], aF7, aF9;
    #pragma unroll
    for (int r = 0; r < 4; ++r) {
        f16x4 g4 = px[r];
        aio[0][r] = (float)g4[0];
        aio[1][r] = (float)g4[1];
        aio[2][r] = (float)g4[2];
        aF7[r] = (float)g4[3];
        aF9[r] = (float)g4[3];
    }
    #pragma unroll
    for (int s = 0; s < 2; ++s) {
        f16x8 v7 = *(const f16x8*)&hR0[l15 * 2 + 0][s * 32 + qd * 8];
        f16x8 v9 = *(const f16x8*)&hR1[l15 * 2 + 1][s * 32 + qd * 8];
        f16x8 vs = v7 + v9;
        aio[0] = __builtin_amdgcn_mfma_f32_16x16x32_f16(vs, bfr[s][0], aio[0], 0, 0, 0);
        aio[1] = __builtin_amdgcn_mfma_f32_16x16x32_f16(vs, bfr[s][1], aio[1], 0, 0, 0);
        aio[2] = __builtin_amdgcn_mfma_f32_16x16x32_f16(vs, bfr[s][2], aio[2], 0, 0, 0);
        aF7 = __builtin_amdgcn_mfma_f32_16x16x32_f16(v7, bfr[s][3], aF7, 0, 0, 0);
        aF9 = __builtin_amdgcn_mfma_f32_16x16x32_f16(v9, bfr[s][3], aF9, 0, 0, 0);
    }
    f32x4 C7, C9;
    #pragma unroll
    for (int r = 0; r < 4; ++r) {
        int pl = qd * 4 + r;
        C7[r] = (float)cR0[pl * 2 + 0][unit];
        C9[r] = (float)cR1[pl * 2 + 1][unit];
    }
    // cn = sigm(I)tanh(U) + sigm(F7)c7 + sigm(F9)c9, one rcp (vectorized):
    f32x4 EA = exp2v(aio[0]);
    f32x4 EO = exp2v(aio[1]);
    f32x4 EB = exp2v(aio[2]);
    f32x4 E7 = exp2v(aF7);
    f32x4 E9 = exp2v(aF9);
    f32x4 PQ  = (1.f + EA) * (1.f + EB);
    f32x4 S7  = 1.f + E7, S9 = 1.f + E9;
    f32x4 S79 = S7 * S9;
    f32x4 NUM = PQ * (C7 * S9 + C9 * S7) + (1.f - EB) * S79;
    f32x4 CN  = NUM * rcpv(PQ * S79);
    f32x4 EE  = exp2v(-N2K * CN);
    f32x4 H   = (1.f - EE) * rcpv((1.f + EE) * (1.f + EO));
    #pragma unroll
    for (int r = 0; r < 4; ++r) {
        int pl = qd * 4 + r;
        out[(size_t)(pair0 + pl) * 192 + unit] = H[r];
    }
}

// ---- tree: grid 2048; side = blockIdx&1 (0=up, 1=down), 16 pairs/block ----
__global__ __launch_bounds__(256, 2) void tree_kernel(
    const int* __restrict__ nb, const int* __restrict__ nt,
    const _Float16* __restrict__ XP, const _Float16* __restrict__ Upk,
    float* __restrict__ out)
{
    __shared__ _Float16 hS[2][NP * 2][68];  // [parity][pl*2+slot][unit]
    __shared__ _Float16 cS[2][NP * 2][68];  // LDS c: only special levels
    __shared__ int btl[16][NP];             // byte offsets into XP rows

    const int tid = threadIdx.x, lane = tid & 63, w = tid >> 6;
    const int l15 = lane & 15, qd = lane >> 4;
    const int unit = w * 16 + l15;
    const int side = blockIdx.x & 1;
    const int pair0 = (blockIdx.x >> 1) * NP;

    {
        int pos = tid >> 4, pl = tid & 15;
        int node = (pair0 + pl) * 16 + pos;
        btl[pos][pl] = (nb[node] * 512 + nt[node]) * 1024;
    }

    // hoist U fragments for THIS side only (32 VGPR)
    f16x8 bfr[2][4];
    #pragma unroll
    for (int s = 0; s < 2; ++s)
        #pragma unroll
        for (int g = 0; g < 4; ++g)
            bfr[s][g] = *(const f16x8*)(Upk + side * 16384 +
                          (g * 64 + unit) * 64 + s * 32 + qd * 8);

    __syncthreads();   // btl visible

    const char* XPs = (const char*)XP + side * 512;  // own preact half

    // register c state: [parity][i*2+p] packed f16x2 (halves = slot)
    f16x2 creg[2][4] = {};
    // ping-pong prefetch: level L consumed from px[L&1]; L=t+1 issued at t.
    f16x4 px[2][8];

    if (side == 0) {
        // ======== UP: levels 0..8; L<7:(L,15-L); L7:7; L8:8(root) ========
        gather_xp<2>(XPs, btl, 0, 15, unit, qd, px[0]);   // L0
        #pragma unroll
        for (int t = 0; t < 9; ++t) {
            const int pt = t & 1, pw = pt ^ 1;
            if (t < 6)       gather_xp<2>(XPs, btl, t + 1, 14 - t, unit, qd, px[pw]);
            else if (t == 6) gather_xp<1>(XPs, btl, 7, 7, unit, qd, px[pw]);
            else if (t == 7) gather_xp<1>(XPs, btl, 8, 8, unit, qd, px[pw]);

            if (t < 7)
                side_level<2>(bfr, px[pt], hS[pt], cS[pt], hS[pw], cS[pw],
                              creg[pt], creg[pw],
                              (t >= 1) ? 1 : 0, (t == 6) ? 1 : 0,
                              out, pair0,
                              t ? 0 : -1, t ? 1 : -1, -1, -1, unit, l15, qd);
            else if (t == 7)
                side_level<1>(bfr, px[pt], hS[pt], cS[pt], hS[pw], cS[pw],
                              creg[pt], creg[pw], 0, 1,
                              out, pair0, 0, 0, -1, -1, unit, l15, qd);
            else
                root_level(bfr, px[pt], hS[0], cS[0], hS[1], cS[1],
                           out, pair0, unit, l15, qd);
            lgkm_barrier();
        }
    } else {
        // ======== DOWN: levels 0..8; L0:8; 1..7:(8-L,8+L); L8:0 ========
        gather_xp<1>(XPs, btl, 8, 8, unit, qd, px[0]);    // L0
        #pragma unroll
        for (int t = 0; t < 9; ++t) {
            const int pt = t & 1, pw = pt ^ 1;
            if (t < 7)       gather_xp<2>(XPs, btl, 7 - t, 9 + t, unit, qd, px[pw]);
            else if (t == 7) gather_xp<1>(XPs, btl, 0, 0, unit, qd, px[pw]);

            if (t == 0)
                side_level<1>(bfr, px[pt], hS[pt], cS[pt], hS[pw], cS[pw],
                              creg[pt], creg[pw], 0, 1,
                              out, pair0, -1, -1, -1, -1, unit, l15, qd);
            else if (t == 8)
                side_level<1>(bfr, px[pt], hS[pt], cS[pt], hS[pw], cS[pw],
                              creg[pt], creg[pw], 0, 0,
                              out, pair0, 0, 0, 64, 64, unit, l15, qd);
            else
                side_level<2>(bfr, px[pt], hS[pt], cS[pt], hS[pw], cS[pw],
                              creg[pt], creg[pw],
                              (t >= 2) ? 1 : 0, (t == 7) ? 1 : 0,
                              out, pair0,
                              0, (t == 1) ? 0 : 1, -1, (t == 7) ? 128 : -1,
                              unit, l15, qd);
            lgkm_barrier();
        }
    }
}

extern "C" void kernel_launch(void* const* d_in, const int* in_sizes, int n_in,
                              void* d_out, int out_size, void* d_ws, size_t ws_size,
                              hipStream_t stream)
{
    const float* tok  = (const float*)d_in[0];
    const float* ohp  = (const float*)d_in[1];
    const float* dep  = (const float*)d_in[2];
    const int*   nb   = (const int*)d_in[3];
    const int*   nt   = (const int*)d_in[4];
    const float* Wi_u = (const float*)d_in[13];
    const float* Ui_u = (const float*)d_in[14];
    const float* bi_u = (const float*)d_in[15];
    const float* Wf_u = (const float*)d_in[16];
    const float* Uf_u = (const float*)d_in[17];
    const float* bf_u = (const float*)d_in[18];
    const float* Wi_d = (const float*)d_in[19];
    const float* Ui_d = (const float*)d_in[20];
    const float* bi_d = (const float*)d_in[21];
    const float* Wf_d = (const float*)d_in[22];
    const float* Uf_d = (const float*)d_in[23];
    const float* bf_d = (const float*)d_in[24];

    char* ws = (char*)d_ws;
    _Float16* Bx  = (_Float16*)(ws);                    // 320 KB
    _Float16* Upk = (_Float16*)(ws + 0x50000);          // 64 KB
    float*    pb  = (float*)   (ws + 0x60000);          // 2 KB
    _Float16* XP  = (_Float16*)(ws + (12u << 20));      // 16 MB
    float* out = (float*)d_out;

    prep_kernel<<<768, 256, 0, stream>>>(Wi_u, Ui_u, bi_u, Wf_u, Uf_u, bf_u,
                                         Wi_d, Ui_d, bi_d, Wf_d, Uf_d, bf_d,
                                         Bx, Upk, pb);
    xp_gemm<<<1024, 256, 0, stream>>>(tok, ohp, dep, Bx, pb, XP);
    tree_kernel<<<2048, 256, 0, stream>>>(nb, nt, XP, Upk, out);

    (void)in_sizes; (void)n_in; (void)out_size; (void)ws_size;
}